// Round 3
// baseline (28323.260 us; speedup 1.0000x reference)
//
#include <hip/hip_runtime.h>
#include <math.h>

namespace {
constexpr int N_    = 2048;
constexpr int H_    = 800;
constexpr int IN_   = 28;
constexpr int TENC  = 28;
constexpr int TTOT  = 78;   // 28 encode + 50 decode
constexpr int ONUM  = 10;
constexpr int BN    = 64;   // samples per tile
constexpr int BI    = 64;   // hidden neurons per tile
constexpr int KC    = 16;   // K chunk (main loop)
constexpr int ROWS  = 28;   // LDS rows: max(KC, IN_)
constexpr int LDP   = 68;   // LDS row stride in doubles (544 B, 16B-aligned rows)
constexpr int ITILES = (H_ + BI - 1) / BI;  // 13
constexpr int NTILES = N_ / BN;             // 32
}

__device__ __forceinline__ double2 ld2d(const double* p) { return *(const double2*)p; }

// ---------------------------------------------------------------------------
// init: fp32 state, constants quantized exactly like the fp32 reference:
//   ro = fl32(exp(fl32(-1/tau)))
// ---------------------------------------------------------------------------
__global__ void init_kernel(float* __restrict__ spk0,
                            float* __restrict__ hm, float* __restrict__ hb,
                            float* __restrict__ om, float* __restrict__ os,
                            float* __restrict__ ob, float* __restrict__ acc,
                            const float* __restrict__ tau_h,
                            const float* __restrict__ tau_o,
                            float* __restrict__ roh, float* __restrict__ roo)
{
    size_t idx = (size_t)blockIdx.x * blockDim.x + threadIdx.x;
    size_t stride = (size_t)gridDim.x * blockDim.x;
    for (size_t k = idx; k < (size_t)N_ * H_; k += stride) {
        spk0[k] = 0.f; hm[k] = 0.f; hb[k] = 0.01f;
    }
    for (size_t k = idx; k < (size_t)N_ * ONUM; k += stride) {
        om[k] = 0.f; os[k] = 0.f; ob[k] = 0.01f; acc[k] = 0.f;
    }
    for (size_t k = idx; k < H_; k += stride) {
        float a = -1.0f / tau_h[k];                 // fp32 division (as in ref)
        roh[k] = (float)exp((double)a);             // correctly-rounded fp32 exp
    }
    for (size_t k = idx; k < ONUM; k += stride) {
        float a = -1.0f / tau_o[k];
        roo[k] = (float)exp((double)a);
    }
}

// ---------------------------------------------------------------------------
// One time step. GEMMs accumulate in fp64 (exact), rounded once to fp32;
// all LIF state updates in fp32, reference expression order, no FMA.
// ---------------------------------------------------------------------------
__global__ __launch_bounds__(256)
void step_kernel(const float* __restrict__ x,
                 const float* __restrict__ Wi,    // [H][28]
                 const float* __restrict__ b_i2h, // [H]
                 const float* __restrict__ Wh,    // [H][H]
                 const float* __restrict__ b_h2h, // [H]
                 const float* __restrict__ Wo,    // [10][H]
                 const float* __restrict__ b_h2o, // [10]
                 const float* __restrict__ roh,   // [H]
                 const float* __restrict__ roo,   // [10]
                 const float* __restrict__ spk_prev,
                 float* __restrict__ spk_new,
                 float* __restrict__ hm, float* __restrict__ hb,
                 float* __restrict__ om, float* __restrict__ os,
                 float* __restrict__ ob, float* __restrict__ acc,
                 int t)
{
    __shared__ __align__(16) double Sl[ROWS * LDP];   // spikes^T / x^T  [row][n]
    __shared__ __align__(16) double Wl[ROWS * LDP];   // weights^T       [row][i]
    __shared__ double Wol[KC * ONUM];                 // output weights  [jj][o]

    const int bx = blockIdx.x;
    const int itile = bx % ITILES, ntile = bx / ITILES;
    const int i0 = itile * BI, n0 = ntile * BN;
    const int tid = threadIdx.x;
    const int tn = tid >> 4;      // 0..15 -> 4 samples each
    const int ti = tid & 15;      // 0..15 -> 4 neurons each

    // fp32 constants exactly as the reference computes them
    const float alpha_arg = -1.0f / 20.0f;
    const float alpha = (float)exp((double)alpha_arg);
    const float onemalpha = 1.0f - alpha;

    double acc16[4][4] = {};
    double oacc[4] = {0.0, 0.0, 0.0, 0.0};
    float inpf[4][4] = {};   // fp32-rounded input projection

    // -------- phase 0: input projection (encode steps only), fp64 accum -----
    if (t < TENC) {
        for (int e = tid; e < BN * IN_; e += 256) {
            int n = e / IN_, c = e % IN_;
            Sl[c * LDP + n] = (double)x[(size_t)(n0 + n) * 784 + c * TENC + t];
        }
        for (int e = tid; e < BI * IN_; e += 256) {
            int i = e / IN_, c = e % IN_;
            Wl[c * LDP + i] = (i0 + i < H_) ? (double)Wi[(i0 + i) * IN_ + c] : 0.0;
        }
        __syncthreads();
        #pragma unroll 4
        for (int c = 0; c < IN_; ++c) {
            double2 a01 = ld2d(&Sl[c * LDP + tn * 4]);
            double2 a23 = ld2d(&Sl[c * LDP + tn * 4 + 2]);
            double2 b01 = ld2d(&Wl[c * LDP + ti * 4]);
            double2 b23 = ld2d(&Wl[c * LDP + ti * 4 + 2]);
            double a0 = a01.x, a1 = a01.y, a2 = a23.x, a3 = a23.y;
            double b0 = b01.x, b1 = b01.y, b2 = b23.x, b3 = b23.y;
            acc16[0][0] += a0 * b0; acc16[0][1] += a0 * b1; acc16[0][2] += a0 * b2; acc16[0][3] += a0 * b3;
            acc16[1][0] += a1 * b0; acc16[1][1] += a1 * b1; acc16[1][2] += a1 * b2; acc16[1][3] += a1 * b3;
            acc16[2][0] += a2 * b0; acc16[2][1] += a2 * b1; acc16[2][2] += a2 * b2; acc16[2][3] += a2 * b3;
            acc16[3][0] += a3 * b0; acc16[3][1] += a3 * b1; acc16[3][2] += a3 * b2; acc16[3][3] += a3 * b3;
        }
        // round input GEMM to fp32 once (matches ref: xt@Wi.T is its own fp32 array)
        #pragma unroll
        for (int q = 0; q < 4; ++q)
            #pragma unroll
            for (int p = 0; p < 4; ++p) { inpf[q][p] = (float)acc16[q][p]; acc16[q][p] = 0.0; }
        __syncthreads();
    }

    // -------- main K loop over hidden spikes (fp64 accum) --------
    for (int j0 = 0; j0 < H_; j0 += KC) {
        for (int e = tid; e < BN * KC; e += 256) {
            int n = e >> 4, jj = e & 15;
            Sl[jj * LDP + n] = (double)spk_prev[(size_t)(n0 + n) * H_ + j0 + jj];
        }
        for (int e = tid; e < BI * KC; e += 256) {
            int i = e >> 4, jj = e & 15;
            Wl[jj * LDP + i] = (i0 + i < H_) ? (double)Wh[(size_t)(i0 + i) * H_ + j0 + jj] : 0.0;
        }
        if (itile == 0) {
            for (int e = tid; e < ONUM * KC; e += 256) {
                int o = e / KC, jj = e % KC;
                Wol[jj * ONUM + o] = (double)Wo[o * H_ + j0 + jj];
            }
        }
        __syncthreads();
        #pragma unroll
        for (int jj = 0; jj < KC; ++jj) {
            double2 a01 = ld2d(&Sl[jj * LDP + tn * 4]);
            double2 a23 = ld2d(&Sl[jj * LDP + tn * 4 + 2]);
            double2 b01 = ld2d(&Wl[jj * LDP + ti * 4]);
            double2 b23 = ld2d(&Wl[jj * LDP + ti * 4 + 2]);
            double a0 = a01.x, a1 = a01.y, a2 = a23.x, a3 = a23.y;
            double b0 = b01.x, b1 = b01.y, b2 = b23.x, b3 = b23.y;
            acc16[0][0] += a0 * b0; acc16[0][1] += a0 * b1; acc16[0][2] += a0 * b2; acc16[0][3] += a0 * b3;
            acc16[1][0] += a1 * b0; acc16[1][1] += a1 * b1; acc16[1][2] += a1 * b2; acc16[1][3] += a1 * b3;
            acc16[2][0] += a2 * b0; acc16[2][1] += a2 * b1; acc16[2][2] += a2 * b2; acc16[2][3] += a2 * b3;
            acc16[3][0] += a3 * b0; acc16[3][1] += a3 * b1; acc16[3][2] += a3 * b2; acc16[3][3] += a3 * b3;
            if (itile == 0 && ti < ONUM) {
                double w = Wol[jj * ONUM + ti];
                oacc[0] += a0 * w; oacc[1] += a1 * w; oacc[2] += a2 * w; oacc[3] += a3 * w;
            }
        }
        __syncthreads();
    }

    // -------- hidden-state epilogue: fp32, reference order, no FMA --------
    {
        #pragma clang fp contract(off)
        float ro4[4] = {}, bi4[4] = {}, bh4[4] = {};
        #pragma unroll
        for (int p = 0; p < 4; ++p) {
            int i = i0 + ti * 4 + p;
            if (i < H_) { ro4[p] = roh[i]; bi4[p] = b_i2h[i]; bh4[p] = b_h2h[i]; }
        }
        #pragma unroll
        for (int q = 0; q < 4; ++q) {
            int n = n0 + tn * 4 + q;
            #pragma unroll
            for (int p = 0; p < 4; ++p) {
                int i = i0 + ti * 4 + p;
                if (i < H_) {
                    size_t idx = (size_t)n * H_ + i;
                    float rec = (float)acc16[q][p];
                    float h_in = ((inpf[q][p] + bi4[p]) + rec) + bh4[p];
                    float sp = spk_prev[idx];
                    float ro = ro4[p];
                    float bnew = (ro * hb[idx]) + ((1.0f - ro) * sp);
                    float B = 0.01f + (1.8f * bnew);
                    float mem = ((hm[idx] * alpha) + (onemalpha * h_in)) - (B * sp);
                    float s = (mem - B) > 0.f ? 1.f : 0.f;
                    hb[idx] = bnew; hm[idx] = mem; spk_new[idx] = s;
                }
            }
        }
    }

    // -------- output-layer epilogue for step t-1: fp32, no FMA --------
    if (itile == 0 && t > 0 && ti < ONUM) {
        #pragma clang fp contract(off)
        const int o = ti;
        const float ro = roo[o];
        const float bo = b_h2o[o];
        const bool msk = (t - 1) >= TENC;
        #pragma unroll
        for (int q = 0; q < 4; ++q) {
            int n = n0 + tn * 4 + q;
            size_t idx = (size_t)n * ONUM + o;
            float o_in = ((float)oacc[q]) + bo;
            float osp = os[idx];
            float bnew = (ro * ob[idx]) + ((1.0f - ro) * osp);
            float B = 0.01f + (1.8f * bnew);
            float mem = ((om[idx] * alpha) + (onemalpha * o_in)) - (B * osp);
            float s = (mem - B) > 0.f ? 1.f : 0.f;
            ob[idx] = bnew; om[idx] = mem; os[idx] = s;
            if (msk) acc[idx] += s;
        }
    }
}

// ---------------------------------------------------------------------------
// Output layer for the final step (t = TTOT-1). One wave per sample.
// ---------------------------------------------------------------------------
__global__ void final_out_kernel(const float* __restrict__ spk,
                                 const float* __restrict__ Wo,
                                 const float* __restrict__ b_h2o,
                                 const float* __restrict__ roo,
                                 const float* __restrict__ om,
                                 const float* __restrict__ os,
                                 const float* __restrict__ ob,
                                 float* __restrict__ acc)
{
    const int n = blockIdx.x;
    const int lane = threadIdx.x; // 64 threads
    const float alpha_f = (float)exp((double)(-1.0f / 20.0f));
    const float onemalpha = 1.0f - alpha_f;
    double p[ONUM] = {};
    for (int j = lane; j < H_; j += 64) {
        double s = (double)spk[(size_t)n * H_ + j];
        #pragma unroll
        for (int o = 0; o < ONUM; ++o) p[o] += s * (double)Wo[o * H_ + j];
    }
    #pragma unroll
    for (int o = 0; o < ONUM; ++o) {
        #pragma unroll
        for (int off = 32; off > 0; off >>= 1) p[o] += __shfl_down(p[o], off, 64);
    }
    if (lane == 0) {
        #pragma clang fp contract(off)
        #pragma unroll
        for (int o = 0; o < ONUM; ++o) {
            size_t idx = (size_t)n * ONUM + o;
            float o_in = ((float)p[o]) + b_h2o[o];
            float osp = os[idx];
            float ro = roo[o];
            float bnew = (ro * ob[idx]) + ((1.0f - ro) * osp);
            float B = 0.01f + (1.8f * bnew);
            float mem = ((om[idx] * alpha_f) + (onemalpha * o_in)) - (B * osp);
            float s = (mem - B) > 0.f ? 1.f : 0.f;
            acc[idx] += s;   // t = 77 >= 28, mask = 1
        }
    }
}

// ---------------------------------------------------------------------------
extern "C" void kernel_launch(void* const* d_in, const int* in_sizes, int n_in,
                              void* d_out, int out_size, void* d_ws, size_t ws_size,
                              hipStream_t stream)
{
    const float* x      = (const float*)d_in[0];
    const float* Wi     = (const float*)d_in[1];
    const float* b_i2h  = (const float*)d_in[2];
    const float* Wh     = (const float*)d_in[3];
    const float* b_h2h  = (const float*)d_in[4];
    const float* Wo     = (const float*)d_in[5];
    const float* b_h2o  = (const float*)d_in[6];
    const float* tau_h  = (const float*)d_in[7];
    const float* tau_o  = (const float*)d_in[8];
    float* acc = (float*)d_out;

    const size_t NH = (size_t)N_ * H_;
    const size_t NO = (size_t)N_ * ONUM;
    float* fws  = (float*)d_ws;
    float* hm   = fws; fws += NH;
    float* hb   = fws; fws += NH;
    float* spk0 = fws; fws += NH;
    float* spk1 = fws; fws += NH;
    float* om   = fws; fws += NO;
    float* os   = fws; fws += NO;
    float* ob   = fws; fws += NO;
    float* roh  = fws; fws += H_;
    float* roo  = fws; fws += ONUM;

    init_kernel<<<512, 256, 0, stream>>>(spk0, hm, hb, om, os, ob, acc,
                                         tau_h, tau_o, roh, roo);
    float* bufs[2] = {spk0, spk1};
    for (int t = 0; t < TTOT; ++t) {
        step_kernel<<<ITILES * NTILES, 256, 0, stream>>>(
            x, Wi, b_i2h, Wh, b_h2h, Wo, b_h2o, roh, roo,
            bufs[t & 1], bufs[(t + 1) & 1], hm, hb, om, os, ob, acc, t);
    }
    final_out_kernel<<<N_, 64, 0, stream>>>(bufs[TTOT & 1], Wo, b_h2o, roo,
                                            om, os, ob, acc);
}

// Round 5
// 2375.300 us; speedup vs baseline: 11.9241x; 11.9241x over previous
//
#include <hip/hip_runtime.h>
#include <math.h>
#include <stdint.h>

namespace {
constexpr int N_    = 2048;
constexpr int H_    = 800;
constexpr int HP    = 832;   // K padded to multiple of 64
constexpr int IN_   = 28;
constexpr int TENC  = 28;
constexpr int TTOT  = 78;    // 28 encode + 50 decode
constexpr int ONUM  = 10;
constexpr size_t PL  = (size_t)H_ * HP;   // one Wh digit plane (bytes)
constexpr size_t PLO = (size_t)16 * HP;   // one Wo digit plane (bytes, rows padded to 16)
}

typedef __attribute__((ext_vector_type(4))) int v4i;

__device__ __forceinline__ v4i ld16(const int8_t* p) { return *(const v4i*)p; }

// balanced base-256 digits of round(w * 2^32); exact for |w| < ~0.49
__device__ __forceinline__ void digitize(float w, int8_t d[4]) {
    double dd = (double)w * 4294967296.0;
    long long r = (long long)rint(dd);
    int8_t d0 = (int8_t)(r & 255); r = (r - (long long)d0) >> 8;
    int8_t d1 = (int8_t)(r & 255); r = (r - (long long)d1) >> 8;
    int8_t d2 = (int8_t)(r & 255); r = (r - (long long)d2) >> 8;
    long long r3 = r; r3 = r3 > 127 ? 127 : (r3 < -128 ? -128 : r3);
    d[0] = d0; d[1] = d1; d[2] = d2; d[3] = (int8_t)r3;
}

// ---------------------------------------------------------------------------
// init: state, fp32-quantized constants, zeroed spike buffers (incl. K-pad),
// and int8 digit planes of Wh / Wo. Re-run every call (ws is re-poisoned).
// ---------------------------------------------------------------------------
__global__ void init_kernel(float* __restrict__ hm, float* __restrict__ hb,
                            float* __restrict__ om, float* __restrict__ os,
                            float* __restrict__ ob, float* __restrict__ acc,
                            float* __restrict__ roh, float* __restrict__ roo,
                            int8_t* __restrict__ spk0, int8_t* __restrict__ spk1,
                            int8_t* __restrict__ whd, int8_t* __restrict__ wod,
                            const float* __restrict__ tau_h,
                            const float* __restrict__ tau_o,
                            const float* __restrict__ Wh,
                            const float* __restrict__ Wo)
{
    size_t idx = (size_t)blockIdx.x * blockDim.x + threadIdx.x;
    size_t stride = (size_t)gridDim.x * blockDim.x;
    for (size_t k = idx; k < (size_t)N_ * H_; k += stride) { hm[k] = 0.f; hb[k] = 0.01f; }
    for (size_t k = idx; k < (size_t)N_ * ONUM; k += stride) {
        om[k] = 0.f; os[k] = 0.f; ob[k] = 0.01f; acc[k] = 0.f;
    }
    for (size_t k = idx; k < H_; k += stride) {
        float a = -1.0f / tau_h[k];
        roh[k] = (float)exp((double)a);
    }
    for (size_t k = idx; k < ONUM; k += stride) {
        float a = -1.0f / tau_o[k];
        roo[k] = (float)exp((double)a);
    }
    for (size_t k = idx; k < (size_t)N_ * HP; k += stride) { spk0[k] = 0; spk1[k] = 0; }
    for (size_t e = idx; e < PL; e += stride) {
        int i = (int)(e / HP), j = (int)(e % HP);
        float w = (j < H_) ? Wh[(size_t)i * H_ + j] : 0.f;
        int8_t d[4]; digitize(w, d);
        whd[e] = d[0]; whd[PL + e] = d[1]; whd[2 * PL + e] = d[2]; whd[3 * PL + e] = d[3];
    }
    for (size_t e = idx; e < PLO; e += stride) {
        int o = (int)(e / HP), j = (int)(e % HP);
        float w = (o < ONUM && j < H_) ? Wo[(size_t)o * H_ + j] : 0.f;
        int8_t d[4]; digitize(w, d);
        wod[e] = d[0]; wod[PLO + e] = d[1]; wod[2 * PLO + e] = d[2]; wod[3 * PLO + e] = d[3];
    }
}

// ---------------------------------------------------------------------------
// One time step. Grid = 26 it-tiles * 16 ngroups; block = 256 (4 waves).
// Wave (it<25): 32 samples x 32 neurons via 2x2 MFMA tiles x 4 digit planes.
// Wave (it==25): output layer for step t-1 (32 samples x 10 outputs).
// Main loop: direct 16B global loads -> v_mfma_i32_16x16x64_i8. No LDS.
// ---------------------------------------------------------------------------
__global__ __launch_bounds__(256)
void step_kernel(const float* __restrict__ x,
                 const float* __restrict__ Wi,     // [H][28]
                 const float* __restrict__ b_i2h,  // [H]
                 const float* __restrict__ b_h2h,  // [H]
                 const float* __restrict__ b_h2o,  // [10]
                 const float* __restrict__ roh,    // [H]
                 const float* __restrict__ roo,    // [10]
                 const int8_t* __restrict__ whd,   // 4 planes [800][832]
                 const int8_t* __restrict__ wod,   // 4 planes [16][832]
                 const int8_t* __restrict__ spk_prev,  // [2048][832]
                 int8_t* __restrict__ spk_new,
                 float* __restrict__ hm, float* __restrict__ hb,
                 float* __restrict__ om, float* __restrict__ os,
                 float* __restrict__ ob, float* __restrict__ acc,
                 int t)
{
    __shared__ float xs[128 * IN_];      // x slice for this block's 128 samples
    __shared__ float wl[IN_ * 32];       // Wi^T tile [c][i_local]

    const int bid  = blockIdx.x;
    const int it   = bid >> 4;           // 0..25 (25 = o-layer)
    const int ng   = bid & 15;
    const int wv   = threadIdx.x >> 6;   // wave 0..3
    const int lane = threadIdx.x & 63;
    const int quad = lane >> 4;
    const int col  = lane & 15;
    const int nt   = ng * 4 + wv;
    const int n0   = nt * 32;
    const int i0   = it * 32;            // valid for it<25
    const bool is_o = (it == 25);
    const bool enc  = (t < TENC) && !is_o;

    const float alpha = (float)exp((double)(-1.0f / 20.0f));
    const float onem  = 1.0f - alpha;
    const double INV32 = 1.0 / 4294967296.0;

    // -------- encode staging: x slice + Wi tile into LDS --------
    if (enc) {
        for (int e = threadIdx.x; e < 128 * IN_; e += 256) {
            int nl = e / IN_, c = e % IN_;
            xs[e] = x[(size_t)(ng * 128 + nl) * 784 + c * TENC + t];
        }
        for (int e = threadIdx.x; e < 32 * IN_; e += 256) {
            int c = e >> 5, il = e & 31;
            wl[c * 32 + il] = Wi[(size_t)(i0 + il) * IN_ + c];
        }
        __syncthreads();
    }

    // -------- input projection (fp64 exact, fp32-rounded once) --------
    float inpf[2][2][4] = {};
    if (enc) {
        #pragma unroll
        for (int a = 0; a < 2; ++a) {
            #pragma unroll
            for (int r = 0; r < 4; ++r) {
                int nl = wv * 32 + a * 16 + quad * 4 + r;
                double s0 = 0.0, s1 = 0.0;
                #pragma unroll
                for (int c = 0; c < IN_; ++c) {
                    double xv = (double)xs[nl * IN_ + c];
                    s0 += xv * (double)wl[c * 32 + col];
                    s1 += xv * (double)wl[c * 32 + 16 + col];
                }
                inpf[a][0][r] = (float)s0;
                inpf[a][1][r] = (float)s1;
            }
        }
    }

    if (!is_o) {
        // -------- hidden GEMM: 2x2 tiles x 4 digits --------
        v4i acc4[2][2][4] = {};
        const int8_t* pa0 = spk_prev + (size_t)(n0 + col) * HP + quad * 16;
        const int8_t* pa1 = pa0 + (size_t)16 * HP;
        const int8_t* pb  = whd + (size_t)(i0 + col) * HP + quad * 16;

        for (int j0 = 0; j0 < HP; j0 += 64) {
            v4i a0 = ld16(pa0 + j0);
            v4i a1 = ld16(pa1 + j0);
            #pragma unroll
            for (int k = 0; k < 4; ++k) {
                v4i b0 = ld16(pb + (size_t)k * PL + j0);
                v4i b1 = ld16(pb + (size_t)k * PL + (size_t)16 * HP + j0);
                acc4[0][0][k] = __builtin_amdgcn_mfma_i32_16x16x64_i8(a0, b0, acc4[0][0][k], 0, 0, 0);
                acc4[0][1][k] = __builtin_amdgcn_mfma_i32_16x16x64_i8(a0, b1, acc4[0][1][k], 0, 0, 0);
                acc4[1][0][k] = __builtin_amdgcn_mfma_i32_16x16x64_i8(a1, b0, acc4[1][0][k], 0, 0, 0);
                acc4[1][1][k] = __builtin_amdgcn_mfma_i32_16x16x64_i8(a1, b1, acc4[1][1][k], 0, 0, 0);
            }
        }

        // -------- hidden-state epilogue: fp32, ref order, no FMA --------
        {
            #pragma clang fp contract(off)
            float roB[2], biB[2], bhB[2];
            #pragma unroll
            for (int b = 0; b < 2; ++b) {
                int i = i0 + b * 16 + col;
                roB[b] = roh[i]; biB[b] = b_i2h[i]; bhB[b] = b_h2h[i];
            }
            #pragma unroll
            for (int a = 0; a < 2; ++a) {
                #pragma unroll
                for (int b = 0; b < 2; ++b) {
                    int i = i0 + b * 16 + col;
                    #pragma unroll
                    for (int r = 0; r < 4; ++r) {
                        int n = n0 + a * 16 + quad * 4 + r;
                        int64_t tot = ((int64_t)acc4[a][b][3][r] << 24)
                                    + ((int64_t)acc4[a][b][2][r] << 16)
                                    + ((int64_t)acc4[a][b][1][r] << 8)
                                    +  (int64_t)acc4[a][b][0][r];
                        float rec = (float)((double)tot * INV32);
                        size_t idx = (size_t)n * H_ + i;
                        float h_in = ((inpf[a][b][r] + biB[b]) + rec) + bhB[b];
                        float sp = (float)spk_prev[(size_t)n * HP + i];
                        float ro = roB[b];
                        float bnew = (ro * hb[idx]) + ((1.0f - ro) * sp);
                        float B = 0.01f + (1.8f * bnew);
                        float mem = ((hm[idx] * alpha) + (onem * h_in)) - (B * sp);
                        float s = (mem - B) > 0.f ? 1.f : 0.f;
                        hb[idx] = bnew; hm[idx] = mem;
                        spk_new[(size_t)n * HP + i] = (int8_t)s;
                    }
                }
            }
        }
    } else {
        // -------- output-layer GEMM for step t-1 --------
        v4i oacc4[2][4] = {};
        const int8_t* pa0 = spk_prev + (size_t)(n0 + col) * HP + quad * 16;
        const int8_t* pa1 = pa0 + (size_t)16 * HP;
        const int8_t* pbo = wod + (size_t)col * HP + quad * 16;

        for (int j0 = 0; j0 < HP; j0 += 64) {
            v4i a0 = ld16(pa0 + j0);
            v4i a1 = ld16(pa1 + j0);
            #pragma unroll
            for (int k = 0; k < 4; ++k) {
                v4i bo = ld16(pbo + (size_t)k * PLO + j0);
                oacc4[0][k] = __builtin_amdgcn_mfma_i32_16x16x64_i8(a0, bo, oacc4[0][k], 0, 0, 0);
                oacc4[1][k] = __builtin_amdgcn_mfma_i32_16x16x64_i8(a1, bo, oacc4[1][k], 0, 0, 0);
            }
        }

        if (t > 0 && col < ONUM) {
            #pragma clang fp contract(off)
            const float ro = roo[col];
            const float bo = b_h2o[col];
            const bool msk = (t - 1) >= TENC;
            #pragma unroll
            for (int a = 0; a < 2; ++a) {
                #pragma unroll
                for (int r = 0; r < 4; ++r) {
                    int n = n0 + a * 16 + quad * 4 + r;
                    int64_t tot = ((int64_t)oacc4[a][3][r] << 24)
                                + ((int64_t)oacc4[a][2][r] << 16)
                                + ((int64_t)oacc4[a][1][r] << 8)
                                +  (int64_t)oacc4[a][0][r];
                    float o_in = ((float)((double)tot * INV32)) + bo;
                    size_t idx = (size_t)n * ONUM + col;
                    float osp = os[idx];
                    float bnew = (ro * ob[idx]) + ((1.0f - ro) * osp);
                    float B = 0.01f + (1.8f * bnew);
                    float mem = ((om[idx] * alpha) + (onem * o_in)) - (B * osp);
                    float s = (mem - B) > 0.f ? 1.f : 0.f;
                    ob[idx] = bnew; om[idx] = mem; os[idx] = s;
                    if (msk) acc[idx] += s;
                }
            }
        }
    }
}

// ---------------------------------------------------------------------------
// Output layer for the final step (t = TTOT-1), fp64-exact dot per sample.
// ---------------------------------------------------------------------------
__global__ void final_out_kernel(const int8_t* __restrict__ spk,
                                 const float* __restrict__ Wo,
                                 const float* __restrict__ b_h2o,
                                 const float* __restrict__ roo,
                                 const float* __restrict__ om,
                                 const float* __restrict__ os,
                                 const float* __restrict__ ob,
                                 float* __restrict__ acc)
{
    const int n = blockIdx.x;
    const int lane = threadIdx.x; // 64
    const float alpha = (float)exp((double)(-1.0f / 20.0f));
    const float onem = 1.0f - alpha;
    double p[ONUM] = {};
    for (int j = lane; j < H_; j += 64) {
        double s = (double)spk[(size_t)n * HP + j];
        #pragma unroll
        for (int o = 0; o < ONUM; ++o) p[o] += s * (double)Wo[(size_t)o * H_ + j];
    }
    #pragma unroll
    for (int o = 0; o < ONUM; ++o) {
        #pragma unroll
        for (int off = 32; off > 0; off >>= 1) p[o] += __shfl_down(p[o], off, 64);
    }
    if (lane == 0) {
        #pragma clang fp contract(off)
        #pragma unroll
        for (int o = 0; o < ONUM; ++o) {
            size_t idx = (size_t)n * ONUM + o;
            float o_in = ((float)p[o]) + b_h2o[o];
            float osp = os[idx];
            float ro = roo[o];
            float bnew = (ro * ob[idx]) + ((1.0f - ro) * osp);
            float B = 0.01f + (1.8f * bnew);
            float mem = ((om[idx] * alpha) + (onem * o_in)) - (B * osp);
            float s = (mem - B) > 0.f ? 1.f : 0.f;
            acc[idx] += s;   // t = 77 >= 28
        }
    }
}

// ---------------------------------------------------------------------------
extern "C" void kernel_launch(void* const* d_in, const int* in_sizes, int n_in,
                              void* d_out, int out_size, void* d_ws, size_t ws_size,
                              hipStream_t stream)
{
    const float* x      = (const float*)d_in[0];
    const float* Wi     = (const float*)d_in[1];
    const float* b_i2h  = (const float*)d_in[2];
    const float* Wh     = (const float*)d_in[3];
    const float* b_h2h  = (const float*)d_in[4];
    const float* Wo     = (const float*)d_in[5];
    const float* b_h2o  = (const float*)d_in[6];
    const float* tau_h  = (const float*)d_in[7];
    const float* tau_o  = (const float*)d_in[8];
    float* acc = (float*)d_out;

    const size_t NH = (size_t)N_ * H_;
    const size_t NO = (size_t)N_ * ONUM;

    uintptr_t p = (uintptr_t)d_ws;
    auto alloc = [&](size_t bytes) -> void* {
        p = (p + 255) & ~(uintptr_t)255;
        void* r = (void*)p; p += bytes; return r;
    };
    float*  hm   = (float*)alloc(NH * 4);
    float*  hb   = (float*)alloc(NH * 4);
    float*  om   = (float*)alloc(NO * 4);
    float*  os   = (float*)alloc(NO * 4);
    float*  ob   = (float*)alloc(NO * 4);
    float*  roh  = (float*)alloc(H_ * 4);
    float*  roo  = (float*)alloc(ONUM * 4);
    int8_t* spk0 = (int8_t*)alloc((size_t)N_ * HP);
    int8_t* spk1 = (int8_t*)alloc((size_t)N_ * HP);
    int8_t* whd  = (int8_t*)alloc(4 * PL);
    int8_t* wod  = (int8_t*)alloc(4 * PLO);

    init_kernel<<<2048, 256, 0, stream>>>(hm, hb, om, os, ob, acc, roh, roo,
                                          spk0, spk1, whd, wod,
                                          tau_h, tau_o, Wh, Wo);
    int8_t* bufs[2] = {spk0, spk1};
    for (int t = 0; t < TTOT; ++t) {
        step_kernel<<<26 * 16, 256, 0, stream>>>(
            x, Wi, b_i2h, b_h2h, b_h2o, roh, roo, whd, wod,
            bufs[t & 1], bufs[(t + 1) & 1], hm, hb, om, os, ob, acc, t);
    }
    final_out_kernel<<<N_, 64, 0, stream>>>(bufs[TTOT & 1], Wo, b_h2o, roo,
                                            om, os, ob, acc);
}